// Round 7
// baseline (190.696 us; speedup 1.0000x reference)
//
#include <hip/hip_runtime.h>
#include <math.h>

// (B,C,H,W)=(8,512,32,32), L=1024, 32 groups, 8 heads, ch=64
#define BATCH   8
#define CCH     512
#define LL      1024
#define NHEADS  8
#define CHD     64
#define EPSV    1e-5f
#define QSCALE  0.1803368801111204f   // 0.125 / ln(2): folded into q so S is in log2 units

typedef __bf16 bf16_t;
typedef bf16_t bf16x8 __attribute__((ext_vector_type(8)));
typedef bf16_t bf16x4 __attribute__((ext_vector_type(4)));
typedef float  f32x4  __attribute__((ext_vector_type(4)));

__device__ __forceinline__ bf16_t f2b(float f) {
  unsigned u = __float_as_uint(f);
  u += 0x7fff + ((u >> 16) & 1);               // RNE
  return __builtin_bit_cast(bf16_t, (unsigned short)(u >> 16));
}

__device__ __forceinline__ unsigned pack2(float lo, float hi) {
  unsigned a = (unsigned)__builtin_bit_cast(unsigned short, f2b(lo));
  unsigned b = (unsigned)__builtin_bit_cast(unsigned short, f2b(hi));
  return (b << 16) | a;
}

__device__ __forceinline__ void gload_lds16(const void* g, void* l) {
  __builtin_amdgcn_global_load_lds(
      (const __attribute__((address_space(1))) void*)g,
      (__attribute__((address_space(3))) void*)l, 16, 0, 0);
}

// ---------------------------------------------------------------------------
// K1: fused GroupNorm stats + normalize + affine + transpose -> xnT bf16.
// One block per (b,g); x slice register-cached (single read).  Grid mapping
// puts the 4 g-quads sharing each 128-B output line on one XCD.
// ---------------------------------------------------------------------------
__global__ __launch_bounds__(256) void gn_norm(const float* __restrict__ x,
                                               const float* __restrict__ gsc,
                                               const float* __restrict__ gbi,
                                               bf16_t* __restrict__ xnT) {
  int lin = blockIdx.x;
  int xcd = lin & 7, slot = lin >> 3;
  int b = slot & 7, jj = slot >> 3;
  int g = xcd * 4 + jj;
  const float4* x4 = (const float4*)(x + ((size_t)(b * 32 + g)) * 16 * LL);
  int tid = threadIdx.x;

  float s = 0.f, ss = 0.f;
  float4 v[16];
#pragma unroll
  for (int it = 0; it < 16; ++it) {
    float4 f = x4[it * 256 + tid];
    v[it] = f;
    s += f.x + f.y + f.z + f.w;
    ss += f.x * f.x + f.y * f.y + f.z * f.z + f.w * f.w;
  }
#pragma unroll
  for (int m = 1; m < 64; m <<= 1) { s += __shfl_xor(s, m); ss += __shfl_xor(ss, m); }
  __shared__ float rs_[4], rss[4];
  int wv = tid >> 6, ln = tid & 63;
  if (ln == 0) { rs_[wv] = s; rss[wv] = ss; }
  __syncthreads();
  s  = rs_[0] + rs_[1] + rs_[2] + rs_[3];
  ss = rss[0] + rss[1] + rss[2] + rss[3];
  float mean = s * (1.f / 16384.f);
  float var  = ss * (1.f / 16384.f) - mean * mean;
  float rstd = rsqrtf(var + EPSV);

  float sc[16], bi[16];
#pragma unroll
  for (int it = 0; it < 16; ++it) {
    sc[it] = gsc[g * 16 + it] * rstd;
    bi[it] = gbi[g * 16 + it] - mean * sc[it];
  }

#pragma unroll
  for (int j = 0; j < 4; ++j) {
    unsigned w[8];
#pragma unroll
    for (int k = 0; k < 8; ++k) {
      float a0 = (j == 0 ? v[2 * k].x : j == 1 ? v[2 * k].y : j == 2 ? v[2 * k].z : v[2 * k].w);
      float a1 = (j == 0 ? v[2 * k + 1].x : j == 1 ? v[2 * k + 1].y : j == 2 ? v[2 * k + 1].z : v[2 * k + 1].w);
      w[k] = pack2(a0 * sc[2 * k] + bi[2 * k], a1 * sc[2 * k + 1] + bi[2 * k + 1]);
    }
    int l = tid * 4 + j;
    bf16_t* dst = xnT + ((size_t)b * LL + l) * CCH + g * 16;
    *(uint4*)dst = make_uint4(w[0], w[1], w[2], w[3]);
    *(uint4*)(dst + 8) = make_uint4(w[4], w[5], w[6], w[7]);
  }
}

// ---------------------------------------------------------------------------
// K2: fp32 -> bf16 weight convert, both weight tensors in one launch.
// ---------------------------------------------------------------------------
__global__ __launch_bounds__(256) void cvt_both(const float* __restrict__ qkvw,
                                                const float* __restrict__ projw,
                                                bf16_t* __restrict__ wqb,
                                                bf16_t* __restrict__ wpb) {
  int i = (blockIdx.x * 256 + threadIdx.x) * 4;
  const float* src;
  bf16_t* dst;
  int j;
  if (i < 1536 * 512) { src = qkvw; dst = wqb; j = i; }
  else                { src = projw; dst = wpb; j = i - 1536 * 512; }
  float4 v = *(const float4*)(src + j);
  bf16x4 o = {f2b(v.x), f2b(v.y), f2b(v.z), f2b(v.w)};
  *(bf16x4*)(dst + j) = o;
}

// ---------------------------------------------------------------------------
// K3: qkv GEMM (MFMA), m97-style LDS staging.  Grid (x=b, y=ot, z=lt) so
// linear%8 == b (XCD/L2 locality on xnT[b]).  128x128 block tile, BK=64,
// global_load_lds width 16 with XOR-granule swizzle on the global source.
// Epilogue: b64 packed stores; q scaled by QSCALE; v transposed+s-permuted.
// ---------------------------------------------------------------------------
__global__ __launch_bounds__(256) void qkv_mfma(const bf16_t* __restrict__ wq,
                                                const bf16_t* __restrict__ xnT,
                                                const float* __restrict__ qkvb,
                                                bf16_t* __restrict__ qt,
                                                bf16_t* __restrict__ kt,
                                                bf16_t* __restrict__ vt) {
  __shared__ bf16_t As[128 * 64];
  __shared__ bf16_t Bs[128 * 64];
  int tid = threadIdx.x;
  int wave = tid >> 6, lane = tid & 63;
  int lrow = lane & 15, quad = lane >> 4;
  int wm = wave >> 1, wn = wave & 1;
  int b = blockIdx.x;
  int oBase = blockIdx.y * 128, lBase = blockIdx.z * 128;
  int srow = lane >> 3;
  int sgOff = (((lane & 7) ^ srow) << 4);

  f32x4 acc[4][4] = {};
  for (int ktile = 0; ktile < 8; ++ktile) {
    int kB = ktile * 64;
    __syncthreads();
#pragma unroll
    for (int j = 0; j < 4; ++j) {
      int ci = wave * 4 + j;
      int R = ci * 8 + srow;
      gload_lds16((const char*)(wq + (size_t)(oBase + R) * CCH + kB) + sgOff,
                  (char*)As + ci * 1024);
      gload_lds16((const char*)(xnT + ((size_t)b * LL + lBase + R) * CCH + kB) + sgOff,
                  (char*)Bs + ci * 1024);
    }
    __syncthreads();
#pragma unroll
    for (int kk = 0; kk < 2; ++kk) {
      bf16x8 af[4], bfr[4];
#pragma unroll
      for (int m = 0; m < 4; ++m) {
        int r = wm * 64 + m * 16 + lrow;
        int g = (kk * 4 + quad) ^ (lrow & 7);
        af[m] = *(const bf16x8*)(As + r * 64 + g * 8);
      }
#pragma unroll
      for (int n = 0; n < 4; ++n) {
        int r = wn * 64 + n * 16 + lrow;
        int g = (kk * 4 + quad) ^ (lrow & 7);
        bfr[n] = *(const bf16x8*)(Bs + r * 64 + g * 8);
      }
#pragma unroll
      for (int m = 0; m < 4; ++m)
#pragma unroll
        for (int n = 0; n < 4; ++n)
          acc[m][n] = __builtin_amdgcn_mfma_f32_16x16x32_bf16(af[m], bfr[n], acc[m][n], 0, 0, 0);
    }
  }

  int oW = oBase + wm * 64;
  int lW = lBase + wn * 64;
  int sec = oW >> 9;
#pragma unroll
  for (int m = 0; m < 4; ++m) {
    int o4 = oW + m * 16 + quad * 4;
    float4 bb4 = *(const float4*)&qkvb[o4];
    int cc = o4 & 511;
    int head = cc >> 6, ch = cc & 63;
    int bh = b * NHEADS + head;
    if (sec == 0) {
#pragma unroll
      for (int n = 0; n < 4; ++n) {
        int l = lW + n * 16 + lrow;
        unsigned d0 = pack2((acc[m][n][0] + bb4.x) * QSCALE,
                            (acc[m][n][1] + bb4.y) * QSCALE);
        unsigned d1 = pack2((acc[m][n][2] + bb4.z) * QSCALE,
                            (acc[m][n][3] + bb4.w) * QSCALE);
        *(uint2*)(qt + ((size_t)bh * LL + l) * CHD + ch) = make_uint2(d0, d1);
      }
    } else if (sec == 1) {
#pragma unroll
      for (int n = 0; n < 4; ++n) {
        int l = lW + n * 16 + lrow;
        unsigned d0 = pack2(acc[m][n][0] + bb4.x, acc[m][n][1] + bb4.y);
        unsigned d1 = pack2(acc[m][n][2] + bb4.z, acc[m][n][3] + bb4.w);
        *(uint2*)(kt + ((size_t)bh * LL + l) * CHD + ch) = make_uint2(d0, d1);
      }
    } else {
      float bb[4] = {bb4.x, bb4.y, bb4.z, bb4.w};
#pragma unroll
      for (int i = 0; i < 4; ++i) {
        unsigned d0 = pack2(acc[m][0][i] + bb[i], acc[m][1][i] + bb[i]);
        unsigned d1 = pack2(acc[m][2][i] + bb[i], acc[m][3][i] + bb[i]);
        *(uint2*)(vt + ((size_t)bh * CHD + ch + i) * LL + lW + lrow * 4) =
            make_uint2(d0, d1);
      }
    }
  }
}

// ---------------------------------------------------------------------------
// K4: flash attention (MFMA), no-max softmax in log2 units, BARRIER-FREE.
// Grid (x=bh, y=t-tile): linear%8 == bh%8 keeps each bh's K/V on one XCD
// (2 MB/XCD in L2); all 4 waves of a block read identical K/V fragment
// addresses -> L1 dedups (16 KB tile < 32 KB L1).  Direct-global frag loads
// (no LDS staging, no __syncthreads): K prefetched one tile ahead, V loaded
// before the softmax section so the P-store lgkmcnt drain doesn't serialize
// it.  Wave owns 32 q-rows (2 subtiles h).  P through wave-private LDS with
// s-permuted layout matching vt's permute; row-sum via ones-MFMA.
// ---------------------------------------------------------------------------
__global__ __launch_bounds__(256, 2) void attn_mfma(const bf16_t* __restrict__ qt,
                                                    const bf16_t* __restrict__ kt,
                                                    const bf16_t* __restrict__ vt,
                                                    bf16_t* __restrict__ at) {
  __shared__ bf16_t pb[8 * 16 * 72];            // per (wave,h) P tile, stride 72
  int tid = threadIdx.x, wave = tid >> 6, lane = tid & 63;
  int lrow = lane & 15, quad = lane >> 4;
  int bh = blockIdx.x;
  int tW = blockIdx.y * 128 + wave * 32;
  const bf16_t* qb = qt + (size_t)bh * LL * CHD;
  const bf16_t* kb = kt + (size_t)bh * LL * CHD;
  const bf16_t* vb = vt + (size_t)bh * CHD * LL;

  bf16x8 qf[2][2];
#pragma unroll
  for (int h = 0; h < 2; ++h) {
    const bf16_t* qp = qb + (size_t)(tW + h * 16 + lrow) * CHD + quad * 8;
    qf[h][0] = *(const bf16x8*)qp;
    qf[h][1] = *(const bf16x8*)(qp + 32);
  }

  bf16x8 ones;
#pragma unroll
  for (int j = 0; j < 8; ++j) ones[j] = (bf16_t)1.0f;

  f32x4 Oa[2][4] = {};
  f32x4 Os[2] = {};

  // K frags for tile 0
  bf16x8 kf0[4], kf1[4];
#pragma unroll
  for (int ss = 0; ss < 4; ++ss) {
    const bf16_t* kp = kb + (size_t)(ss * 16 + lrow) * CHD + quad * 8;
    kf0[ss] = *(const bf16x8*)kp;
    kf1[ss] = *(const bf16x8*)(kp + 32);
  }

  for (int st = 0; st < 16; ++st) {
    int sB = st * 64;

    // V frags for current tile: issue early, consumed after the P section.
    bf16x8 vf0[4], vf1[4];
#pragma unroll
    for (int n = 0; n < 4; ++n) {
      const bf16_t* vp = vb + (size_t)(n * 16 + lrow) * LL + sB + quad * 8;
      vf0[n] = *(const bf16x8*)vp;
      vf1[n] = *(const bf16x8*)(vp + 32);
    }

    // QK^T
    f32x4 S[2][4];
#pragma unroll
    for (int ss = 0; ss < 4; ++ss) {
#pragma unroll
      for (int h = 0; h < 2; ++h) {
        f32x4 z = {0.f, 0.f, 0.f, 0.f};
        z = __builtin_amdgcn_mfma_f32_16x16x32_bf16(qf[h][0], kf0[ss], z, 0, 0, 0);
        S[h][ss] = __builtin_amdgcn_mfma_f32_16x16x32_bf16(qf[h][1], kf1[ss], z, 0, 0, 0);
      }
    }

    // prefetch next tile's K frags (hides under softmax)
    int sBn = (st < 15) ? sB + 64 : 0;
#pragma unroll
    for (int ss = 0; ss < 4; ++ss) {
      const bf16_t* kp = kb + (size_t)(sBn + ss * 16 + lrow) * CHD + quad * 8;
      kf0[ss] = *(const bf16x8*)kp;
      kf1[ss] = *(const bf16x8*)(kp + 32);
    }

    // p = exp2(S); pack truncated bf16 pairs; store s-permuted to private LDS
#pragma unroll
    for (int h = 0; h < 2; ++h) {
      bf16_t* pw = pb + (wave * 2 + h) * (16 * 72);
      float p[4][4];
#pragma unroll
      for (int ss = 0; ss < 4; ++ss)
#pragma unroll
        for (int i = 0; i < 4; ++i)
          p[ss][i] = __builtin_amdgcn_exp2f(S[h][ss][i]);
#pragma unroll
      for (int i = 0; i < 4; ++i) {
        unsigned d0 = __builtin_amdgcn_perm(__float_as_uint(p[1][i]),
                                            __float_as_uint(p[0][i]), 0x07060302u);
        unsigned d1 = __builtin_amdgcn_perm(__float_as_uint(p[3][i]),
                                            __float_as_uint(p[2][i]), 0x07060302u);
        uint2* dst = (uint2*)(pw + (quad * 4 + i) * 72 + lrow * 4);
        *dst = make_uint2(d0, d1);
      }
    }
    asm volatile("s_waitcnt lgkmcnt(0)" ::: "memory");   // wave-private P only

    bf16x8 pf[2][2];
#pragma unroll
    for (int h = 0; h < 2; ++h) {
      const bf16_t* pw = pb + (wave * 2 + h) * (16 * 72);
      pf[h][0] = *(const bf16x8*)(pw + lrow * 72 + quad * 8);
      pf[h][1] = *(const bf16x8*)(pw + lrow * 72 + 32 + quad * 8);
    }

    // PV (V frags already resident) + row-sum via ones-MFMA
#pragma unroll
    for (int n = 0; n < 4; ++n) {
#pragma unroll
      for (int h = 0; h < 2; ++h) {
        Oa[h][n] = __builtin_amdgcn_mfma_f32_16x16x32_bf16(pf[h][0], vf0[n], Oa[h][n], 0, 0, 0);
        Oa[h][n] = __builtin_amdgcn_mfma_f32_16x16x32_bf16(pf[h][1], vf1[n], Oa[h][n], 0, 0, 0);
      }
    }
#pragma unroll
    for (int h = 0; h < 2; ++h) {
      Os[h] = __builtin_amdgcn_mfma_f32_16x16x32_bf16(pf[h][0], ones, Os[h], 0, 0, 0);
      Os[h] = __builtin_amdgcn_mfma_f32_16x16x32_bf16(pf[h][1], ones, Os[h], 0, 0, 0);
    }
  }

  bf16_t* ab = at + (size_t)bh * LL * CHD;
#pragma unroll
  for (int h = 0; h < 2; ++h) {
    float inv[4];
#pragma unroll
    for (int i = 0; i < 4; ++i) inv[i] = 1.f / Os[h][i];
#pragma unroll
    for (int n = 0; n < 4; ++n)
#pragma unroll
      for (int i = 0; i < 4; ++i)
        ab[(size_t)(tW + h * 16 + quad * 4 + i) * CHD + n * 16 + lrow] =
            f2b(Oa[h][n][i] * inv[i]);
  }
}

// ---------------------------------------------------------------------------
// K5: proj GEMM (MFMA) + bias + fp32 residual, LDS-staged like K3.
// BK=64 == one head of at.  Grid (x=b, y=ot, z=lt), linear%8 == b.
// ---------------------------------------------------------------------------
__global__ __launch_bounds__(256) void proj_mfma(const bf16_t* __restrict__ wp,
                                                 const bf16_t* __restrict__ at,
                                                 const float* __restrict__ projb,
                                                 const float* __restrict__ x,
                                                 float* __restrict__ out) {
  __shared__ bf16_t As[128 * 64];
  __shared__ bf16_t Bs[128 * 64];
  int tid = threadIdx.x;
  int wave = tid >> 6, lane = tid & 63;
  int lrow = lane & 15, quad = lane >> 4;
  int wm = wave >> 1, wn = wave & 1;
  int b = blockIdx.x;
  int oBase = blockIdx.y * 128, lBase = blockIdx.z * 128;
  int srow = lane >> 3;
  int sgOff = (((lane & 7) ^ srow) << 4);

  f32x4 acc[4][4] = {};
  for (int ktile = 0; ktile < 8; ++ktile) {     // head = ktile
    int kB = ktile * 64;
    __syncthreads();
#pragma unroll
    for (int j = 0; j < 4; ++j) {
      int ci = wave * 4 + j;
      int R = ci * 8 + srow;
      gload_lds16((const char*)(wp + (size_t)(oBase + R) * CCH + kB) + sgOff,
                  (char*)As + ci * 1024);
      gload_lds16((const char*)(at + ((size_t)(b * NHEADS + ktile) * LL + lBase + R) * CHD) + sgOff,
                  (char*)Bs + ci * 1024);
    }
    __syncthreads();
#pragma unroll
    for (int kk = 0; kk < 2; ++kk) {
      bf16x8 af[4], bfr[4];
#pragma unroll
      for (int m = 0; m < 4; ++m) {
        int r = wm * 64 + m * 16 + lrow;
        int g = (kk * 4 + quad) ^ (lrow & 7);
        af[m] = *(const bf16x8*)(As + r * 64 + g * 8);
      }
#pragma unroll
      for (int n = 0; n < 4; ++n) {
        int r = wn * 64 + n * 16 + lrow;
        int g = (kk * 4 + quad) ^ (lrow & 7);
        bfr[n] = *(const bf16x8*)(Bs + r * 64 + g * 8);
      }
#pragma unroll
      for (int m = 0; m < 4; ++m)
#pragma unroll
        for (int n = 0; n < 4; ++n)
          acc[m][n] = __builtin_amdgcn_mfma_f32_16x16x32_bf16(af[m], bfr[n], acc[m][n], 0, 0, 0);
    }
  }

  int oW = oBase + wm * 64;
  int lW = lBase + wn * 64;
#pragma unroll
  for (int m = 0; m < 4; ++m) {
#pragma unroll
    for (int i = 0; i < 4; ++i) {
      int o = oW + m * 16 + quad * 4 + i;
      float bb = projb[o];
#pragma unroll
      for (int n = 0; n < 4; ++n) {
        int l = lW + n * 16 + lrow;
        size_t off = ((size_t)(b * CCH + o)) * LL + l;
        out[off] = acc[m][n][i] + bb + x[off];
      }
    }
  }
}

// ---------------------------------------------------------------------------
extern "C" void kernel_launch(void* const* d_in, const int* in_sizes, int n_in,
                              void* d_out, int out_size, void* d_ws, size_t ws_size,
                              hipStream_t stream) {
  const float* x     = (const float*)d_in[0];
  const float* gsc   = (const float*)d_in[1];
  const float* gbi   = (const float*)d_in[2];
  const float* qkvw  = (const float*)d_in[3];
  const float* qkvb  = (const float*)d_in[4];
  const float* projw = (const float*)d_in[5];
  const float* projb = (const float*)d_in[6];
  float* out = (float*)d_out;

  char* ws = (char*)d_ws;
  bf16_t* wqb   = (bf16_t*)(ws + 4096);
  bf16_t* wpb   = (bf16_t*)(ws + 4096 + 1572864);
  bf16_t* xnT   = (bf16_t*)(ws + 2101248);
  bf16_t* qt    = (bf16_t*)(ws + 2101248 + 8388608);
  bf16_t* kt    = (bf16_t*)(ws + 2101248 + 2 * 8388608);
  bf16_t* vt    = (bf16_t*)(ws + 2101248 + 3 * 8388608);
  bf16_t* at    = (bf16_t*)(ws + 2101248 + 4 * 8388608);

  hipLaunchKernelGGL(cvt_both, dim3(1024), dim3(256), 0, stream, qkvw, projw, wqb, wpb);
  hipLaunchKernelGGL(gn_norm, dim3(256), dim3(256), 0, stream, x, gsc, gbi, xnT);
  hipLaunchKernelGGL(qkv_mfma, dim3(BATCH, 12, 8), dim3(256), 0, stream,
                     wqb, xnT, qkvb, qt, kt, vt);
  hipLaunchKernelGGL(attn_mfma, dim3(64, 8), dim3(256), 0, stream, qt, kt, vt, at);
  hipLaunchKernelGGL(proj_mfma, dim3(BATCH, 4, 8), dim3(256), 0, stream,
                     wpb, at, projb, x, out);
}

// Round 8
// 165.996 us; speedup vs baseline: 1.1488x; 1.1488x over previous
//
#include <hip/hip_runtime.h>
#include <math.h>

// (B,C,H,W)=(8,512,32,32), L=1024, 32 groups, 8 heads, ch=64
#define BATCH   8
#define CCH     512
#define LL      1024
#define NHEADS  8
#define CHD     64
#define EPSV    1e-5f
#define QSCALE  0.1803368801111204f   // 0.125 / ln(2): folded into q so S is in log2 units

typedef __bf16 bf16_t;
typedef bf16_t bf16x8 __attribute__((ext_vector_type(8)));
typedef bf16_t bf16x4 __attribute__((ext_vector_type(4)));
typedef float  f32x4  __attribute__((ext_vector_type(4)));

__device__ __forceinline__ bf16_t f2b(float f) {
  unsigned u = __float_as_uint(f);
  u += 0x7fff + ((u >> 16) & 1);               // RNE
  return __builtin_bit_cast(bf16_t, (unsigned short)(u >> 16));
}

__device__ __forceinline__ unsigned pack2(float lo, float hi) {
  unsigned a = (unsigned)__builtin_bit_cast(unsigned short, f2b(lo));
  unsigned b = (unsigned)__builtin_bit_cast(unsigned short, f2b(hi));
  return (b << 16) | a;
}

__device__ __forceinline__ void gload_lds16(const void* g, void* l) {
  __builtin_amdgcn_global_load_lds(
      (const __attribute__((address_space(1))) void*)g,
      (__attribute__((address_space(3))) void*)l, 16, 0, 0);
}

// ---------------------------------------------------------------------------
// K1: fused prep.  Blocks 0..1023: fp32->bf16 weight convert (qkv_w + proj_w).
// Blocks 1024..1279: GroupNorm stats+normalize+affine+transpose -> xnT bf16
// (one block per (b,g), x slice register-cached; 4 g-quads sharing a 128-B
// output line mapped to one XCD).
// ---------------------------------------------------------------------------
__global__ __launch_bounds__(256) void prep_fused(const float* __restrict__ qkvw,
                                                  const float* __restrict__ projw,
                                                  bf16_t* __restrict__ wqb,
                                                  bf16_t* __restrict__ wpb,
                                                  const float* __restrict__ x,
                                                  const float* __restrict__ gsc,
                                                  const float* __restrict__ gbi,
                                                  bf16_t* __restrict__ xnT) {
  int bid = blockIdx.x;
  int tid = threadIdx.x;
  if (bid < 1024) {
    int i = (bid * 256 + tid) * 4;
    const float* src;
    bf16_t* dst;
    int j;
    if (i < 1536 * 512) { src = qkvw; dst = wqb; j = i; }
    else                { src = projw; dst = wpb; j = i - 1536 * 512; }
    float4 v = *(const float4*)(src + j);
    bf16x4 o = {f2b(v.x), f2b(v.y), f2b(v.z), f2b(v.w)};
    *(bf16x4*)(dst + j) = o;
    return;
  }
  int lin = bid - 1024;
  int xcd = lin & 7, slot = lin >> 3;
  int b = slot & 7, jj = slot >> 3;
  int g = xcd * 4 + jj;
  const float4* x4 = (const float4*)(x + ((size_t)(b * 32 + g)) * 16 * LL);

  float s = 0.f, ss = 0.f;
  float4 v[16];
#pragma unroll
  for (int it = 0; it < 16; ++it) {
    float4 f = x4[it * 256 + tid];
    v[it] = f;
    s += f.x + f.y + f.z + f.w;
    ss += f.x * f.x + f.y * f.y + f.z * f.z + f.w * f.w;
  }
#pragma unroll
  for (int m = 1; m < 64; m <<= 1) { s += __shfl_xor(s, m); ss += __shfl_xor(ss, m); }
  __shared__ float rs_[4], rss[4];
  int wv = tid >> 6, ln = tid & 63;
  if (ln == 0) { rs_[wv] = s; rss[wv] = ss; }
  __syncthreads();
  s  = rs_[0] + rs_[1] + rs_[2] + rs_[3];
  ss = rss[0] + rss[1] + rss[2] + rss[3];
  float mean = s * (1.f / 16384.f);
  float var  = ss * (1.f / 16384.f) - mean * mean;
  float rstd = rsqrtf(var + EPSV);

  float sc[16], bi[16];
#pragma unroll
  for (int it = 0; it < 16; ++it) {
    sc[it] = gsc[g * 16 + it] * rstd;
    bi[it] = gbi[g * 16 + it] - mean * sc[it];
  }

#pragma unroll
  for (int j = 0; j < 4; ++j) {
    unsigned w[8];
#pragma unroll
    for (int k = 0; k < 8; ++k) {
      float a0 = (j == 0 ? v[2 * k].x : j == 1 ? v[2 * k].y : j == 2 ? v[2 * k].z : v[2 * k].w);
      float a1 = (j == 0 ? v[2 * k + 1].x : j == 1 ? v[2 * k + 1].y : j == 2 ? v[2 * k + 1].z : v[2 * k + 1].w);
      w[k] = pack2(a0 * sc[2 * k] + bi[2 * k], a1 * sc[2 * k + 1] + bi[2 * k + 1]);
    }
    int l = tid * 4 + j;
    bf16_t* dst = xnT + ((size_t)b * LL + l) * CCH + g * 16;
    *(uint4*)dst = make_uint4(w[0], w[1], w[2], w[3]);
    *(uint4*)(dst + 8) = make_uint4(w[4], w[5], w[6], w[7]);
  }
}

// ---------------------------------------------------------------------------
// K2: qkv GEMM (MFMA), m97-style LDS staging.  Grid (x=b, y=ot, z=lt) so
// linear%8 == b (XCD/L2 locality on xnT[b]).  128x128 block tile, BK=64,
// global_load_lds width 16 with XOR-granule swizzle on the global source.
// Epilogue: b64 packed stores; q scaled by QSCALE; v transposed+s-permuted.
// ---------------------------------------------------------------------------
__global__ __launch_bounds__(256) void qkv_mfma(const bf16_t* __restrict__ wq,
                                                const bf16_t* __restrict__ xnT,
                                                const float* __restrict__ qkvb,
                                                bf16_t* __restrict__ qt,
                                                bf16_t* __restrict__ kt,
                                                bf16_t* __restrict__ vt) {
  __shared__ bf16_t As[128 * 64];
  __shared__ bf16_t Bs[128 * 64];
  int tid = threadIdx.x;
  int wave = tid >> 6, lane = tid & 63;
  int lrow = lane & 15, quad = lane >> 4;
  int wm = wave >> 1, wn = wave & 1;
  int b = blockIdx.x;
  int oBase = blockIdx.y * 128, lBase = blockIdx.z * 128;
  int srow = lane >> 3;
  int sgOff = (((lane & 7) ^ srow) << 4);

  f32x4 acc[4][4] = {};
  for (int ktile = 0; ktile < 8; ++ktile) {
    int kB = ktile * 64;
    __syncthreads();
#pragma unroll
    for (int j = 0; j < 4; ++j) {
      int ci = wave * 4 + j;
      int R = ci * 8 + srow;
      gload_lds16((const char*)(wq + (size_t)(oBase + R) * CCH + kB) + sgOff,
                  (char*)As + ci * 1024);
      gload_lds16((const char*)(xnT + ((size_t)b * LL + lBase + R) * CCH + kB) + sgOff,
                  (char*)Bs + ci * 1024);
    }
    __syncthreads();
#pragma unroll
    for (int kk = 0; kk < 2; ++kk) {
      bf16x8 af[4], bfr[4];
#pragma unroll
      for (int m = 0; m < 4; ++m) {
        int r = wm * 64 + m * 16 + lrow;
        int g = (kk * 4 + quad) ^ (lrow & 7);
        af[m] = *(const bf16x8*)(As + r * 64 + g * 8);
      }
#pragma unroll
      for (int n = 0; n < 4; ++n) {
        int r = wn * 64 + n * 16 + lrow;
        int g = (kk * 4 + quad) ^ (lrow & 7);
        bfr[n] = *(const bf16x8*)(Bs + r * 64 + g * 8);
      }
#pragma unroll
      for (int m = 0; m < 4; ++m)
#pragma unroll
        for (int n = 0; n < 4; ++n)
          acc[m][n] = __builtin_amdgcn_mfma_f32_16x16x32_bf16(af[m], bfr[n], acc[m][n], 0, 0, 0);
    }
  }

  int oW = oBase + wm * 64;
  int lW = lBase + wn * 64;
  int sec = oW >> 9;
#pragma unroll
  for (int m = 0; m < 4; ++m) {
    int o4 = oW + m * 16 + quad * 4;
    float4 bb4 = *(const float4*)&qkvb[o4];
    int cc = o4 & 511;
    int head = cc >> 6, ch = cc & 63;
    int bh = b * NHEADS + head;
    if (sec == 0) {
#pragma unroll
      for (int n = 0; n < 4; ++n) {
        int l = lW + n * 16 + lrow;
        unsigned d0 = pack2((acc[m][n][0] + bb4.x) * QSCALE,
                            (acc[m][n][1] + bb4.y) * QSCALE);
        unsigned d1 = pack2((acc[m][n][2] + bb4.z) * QSCALE,
                            (acc[m][n][3] + bb4.w) * QSCALE);
        *(uint2*)(qt + ((size_t)bh * LL + l) * CHD + ch) = make_uint2(d0, d1);
      }
    } else if (sec == 1) {
#pragma unroll
      for (int n = 0; n < 4; ++n) {
        int l = lW + n * 16 + lrow;
        unsigned d0 = pack2(acc[m][n][0] + bb4.x, acc[m][n][1] + bb4.y);
        unsigned d1 = pack2(acc[m][n][2] + bb4.z, acc[m][n][3] + bb4.w);
        *(uint2*)(kt + ((size_t)bh * LL + l) * CHD + ch) = make_uint2(d0, d1);
      }
    } else {
      float bb[4] = {bb4.x, bb4.y, bb4.z, bb4.w};
#pragma unroll
      for (int i = 0; i < 4; ++i) {
        unsigned d0 = pack2(acc[m][0][i] + bb[i], acc[m][1][i] + bb[i]);
        unsigned d1 = pack2(acc[m][2][i] + bb[i], acc[m][3][i] + bb[i]);
        *(uint2*)(vt + ((size_t)bh * CHD + ch + i) * LL + lW + lrow * 4) =
            make_uint2(d0, d1);
      }
    }
  }
}

// ---------------------------------------------------------------------------
// K3: flash attention (MFMA), no-max softmax in log2 units.
// Hybrid memory plan: K staged in double-buffered LDS via global_load_lds
// (QK consumes it immediately -> needs the decoupled staging); V read DIRECT
// from global (issued at tile top, consumed ~600 cyc later after the P
// section -> L1/L2 latency coverable; 4 waves read identical addrs -> L1
// dedup).  Wave owns 32 q-rows (2 subtiles h) sharing K/V frags.
// Grid (x=bh, y=t-tile): linear%8 == bh%8 keeps K/V per-XCD (2 MB < L2).
// exp2-only softmax; row-sum via ones-MFMA; P via wave-private LDS.
// ---------------------------------------------------------------------------
__global__ __launch_bounds__(256) void attn_mfma(const bf16_t* __restrict__ qt,
                                                 const bf16_t* __restrict__ kt,
                                                 const bf16_t* __restrict__ vt,
                                                 bf16_t* __restrict__ at) {
  __shared__ bf16_t kbuf[2][64 * 64];           // [s][ch], granule-swizzled
  __shared__ bf16_t pb[8 * 16 * 72];            // per (wave,h) P tile, stride 72
  int tid = threadIdx.x, wave = tid >> 6, lane = tid & 63;
  int lrow = lane & 15, quad = lane >> 4;
  int bh = blockIdx.x;
  int tW = blockIdx.y * 128 + wave * 32;
  const bf16_t* qb = qt + (size_t)bh * LL * CHD;
  const bf16_t* kb = kt + (size_t)bh * LL * CHD;
  const bf16_t* vb = vt + (size_t)bh * CHD * LL;

  int srow = lane >> 3;
  int sgb = (((lane & 7) ^ srow) << 4);

  bf16x8 qf[2][2];
#pragma unroll
  for (int h = 0; h < 2; ++h) {
    const bf16_t* qp = qb + (size_t)(tW + h * 16 + lrow) * CHD + quad * 8;
    qf[h][0] = *(const bf16x8*)qp;
    qf[h][1] = *(const bf16x8*)(qp + 32);
  }

  bf16x8 ones;
#pragma unroll
  for (int j = 0; j < 8; ++j) ones[j] = (bf16_t)1.0f;

  f32x4 Oa[2][4] = {};
  f32x4 Os[2] = {};

  // stage K tile 0 (each wave covers 2 of 8 1-KB chunks)
#pragma unroll
  for (int j = 0; j < 2; ++j) {
    int c = wave * 2 + j;
    int R = c * 8 + srow;
    gload_lds16((const char*)(kb + (size_t)R * CHD) + sgb, (char*)&kbuf[0][0] + c * 1024);
  }
  __syncthreads();

  int swz0 = (quad ^ (lrow & 7)) * 8;
  int swz1 = ((quad + 4) ^ (lrow & 7)) * 8;

  for (int st = 0; st < 16; ++st) {
    int cur = st & 1;
    int sB = st * 64;

    // V frags for current tile: direct global, issued early, consumed post-P
    bf16x8 vf0[4], vf1[4];
#pragma unroll
    for (int n = 0; n < 4; ++n) {
      const bf16_t* vp = vb + (size_t)(n * 16 + lrow) * LL + sB + quad * 8;
      vf0[n] = *(const bf16x8*)vp;
      vf1[n] = *(const bf16x8*)(vp + 32);
    }

    // stage next K tile into other buffer
    if (st < 15) {
      int sBn = sB + 64;
#pragma unroll
      for (int j = 0; j < 2; ++j) {
        int c = wave * 2 + j;
        int R = c * 8 + srow;
        gload_lds16((const char*)(kb + (size_t)(sBn + R) * CHD) + sgb,
                    (char*)&kbuf[cur ^ 1][0] + c * 1024);
      }
    }
    const bf16_t* kbase = &kbuf[cur][0];

    // QK^T from staged K
    f32x4 S[2][4];
#pragma unroll
    for (int ss = 0; ss < 4; ++ss) {
      int s = ss * 16 + lrow;
      bf16x8 k0 = *(const bf16x8*)(kbase + s * 64 + swz0);
      bf16x8 k1 = *(const bf16x8*)(kbase + s * 64 + swz1);
#pragma unroll
      for (int h = 0; h < 2; ++h) {
        f32x4 z = {0.f, 0.f, 0.f, 0.f};
        z = __builtin_amdgcn_mfma_f32_16x16x32_bf16(qf[h][0], k0, z, 0, 0, 0);
        S[h][ss] = __builtin_amdgcn_mfma_f32_16x16x32_bf16(qf[h][1], k1, z, 0, 0, 0);
      }
    }

    // p = exp2(S); pack truncated bf16 pairs; store s-permuted to private LDS
#pragma unroll
    for (int h = 0; h < 2; ++h) {
      bf16_t* pw = pb + (wave * 2 + h) * (16 * 72);
      float p[4][4];
#pragma unroll
      for (int ss = 0; ss < 4; ++ss)
#pragma unroll
        for (int i = 0; i < 4; ++i)
          p[ss][i] = __builtin_amdgcn_exp2f(S[h][ss][i]);
#pragma unroll
      for (int i = 0; i < 4; ++i) {
        unsigned d0 = __builtin_amdgcn_perm(__float_as_uint(p[1][i]),
                                            __float_as_uint(p[0][i]), 0x07060302u);
        unsigned d1 = __builtin_amdgcn_perm(__float_as_uint(p[3][i]),
                                            __float_as_uint(p[2][i]), 0x07060302u);
        uint2* dst = (uint2*)(pw + (quad * 4 + i) * 72 + lrow * 4);
        *dst = make_uint2(d0, d1);
      }
    }
    asm volatile("s_waitcnt lgkmcnt(0)" ::: "memory");   // wave-private P only

    bf16x8 pf[2][2];
#pragma unroll
    for (int h = 0; h < 2; ++h) {
      const bf16_t* pw = pb + (wave * 2 + h) * (16 * 72);
      pf[h][0] = *(const bf16x8*)(pw + lrow * 72 + quad * 8);
      pf[h][1] = *(const bf16x8*)(pw + lrow * 72 + 32 + quad * 8);
    }

    // PV (V frags issued at tile top) + row-sum via ones-MFMA
#pragma unroll
    for (int n = 0; n < 4; ++n) {
#pragma unroll
      for (int h = 0; h < 2; ++h) {
        Oa[h][n] = __builtin_amdgcn_mfma_f32_16x16x32_bf16(pf[h][0], vf0[n], Oa[h][n], 0, 0, 0);
        Oa[h][n] = __builtin_amdgcn_mfma_f32_16x16x32_bf16(pf[h][1], vf1[n], Oa[h][n], 0, 0, 0);
      }
    }
#pragma unroll
    for (int h = 0; h < 2; ++h) {
      Os[h] = __builtin_amdgcn_mfma_f32_16x16x32_bf16(pf[h][0], ones, Os[h], 0, 0, 0);
      Os[h] = __builtin_amdgcn_mfma_f32_16x16x32_bf16(pf[h][1], ones, Os[h], 0, 0, 0);
    }

    __syncthreads();   // staged K(st+1) landed; all waves done with kbuf[cur]
  }

  bf16_t* ab = at + (size_t)bh * LL * CHD;
#pragma unroll
  for (int h = 0; h < 2; ++h) {
    float inv[4];
#pragma unroll
    for (int i = 0; i < 4; ++i) inv[i] = 1.f / Os[h][i];
#pragma unroll
    for (int n = 0; n < 4; ++n)
#pragma unroll
      for (int i = 0; i < 4; ++i)
        ab[(size_t)(tW + h * 16 + quad * 4 + i) * CHD + n * 16 + lrow] =
            f2b(Oa[h][n][i] * inv[i]);
  }
}

// ---------------------------------------------------------------------------
// K4: proj GEMM (MFMA) + bias + fp32 residual, LDS-staged like K2.
// BK=64 == one head of at.  Grid (x=b, y=ot, z=lt), linear%8 == b.
// ---------------------------------------------------------------------------
__global__ __launch_bounds__(256) void proj_mfma(const bf16_t* __restrict__ wp,
                                                 const bf16_t* __restrict__ at,
                                                 const float* __restrict__ projb,
                                                 const float* __restrict__ x,
                                                 float* __restrict__ out) {
  __shared__ bf16_t As[128 * 64];
  __shared__ bf16_t Bs[128 * 64];
  int tid = threadIdx.x;
  int wave = tid >> 6, lane = tid & 63;
  int lrow = lane & 15, quad = lane >> 4;
  int wm = wave >> 1, wn = wave & 1;
  int b = blockIdx.x;
  int oBase = blockIdx.y * 128, lBase = blockIdx.z * 128;
  int srow = lane >> 3;
  int sgOff = (((lane & 7) ^ srow) << 4);

  f32x4 acc[4][4] = {};
  for (int ktile = 0; ktile < 8; ++ktile) {     // head = ktile
    int kB = ktile * 64;
    __syncthreads();
#pragma unroll
    for (int j = 0; j < 4; ++j) {
      int ci = wave * 4 + j;
      int R = ci * 8 + srow;
      gload_lds16((const char*)(wp + (size_t)(oBase + R) * CCH + kB) + sgOff,
                  (char*)As + ci * 1024);
      gload_lds16((const char*)(at + ((size_t)(b * NHEADS + ktile) * LL + lBase + R) * CHD) + sgOff,
                  (char*)Bs + ci * 1024);
    }
    __syncthreads();
#pragma unroll
    for (int kk = 0; kk < 2; ++kk) {
      bf16x8 af[4], bfr[4];
#pragma unroll
      for (int m = 0; m < 4; ++m) {
        int r = wm * 64 + m * 16 + lrow;
        int g = (kk * 4 + quad) ^ (lrow & 7);
        af[m] = *(const bf16x8*)(As + r * 64 + g * 8);
      }
#pragma unroll
      for (int n = 0; n < 4; ++n) {
        int r = wn * 64 + n * 16 + lrow;
        int g = (kk * 4 + quad) ^ (lrow & 7);
        bfr[n] = *(const bf16x8*)(Bs + r * 64 + g * 8);
      }
#pragma unroll
      for (int m = 0; m < 4; ++m)
#pragma unroll
        for (int n = 0; n < 4; ++n)
          acc[m][n] = __builtin_amdgcn_mfma_f32_16x16x32_bf16(af[m], bfr[n], acc[m][n], 0, 0, 0);
    }
  }

  int oW = oBase + wm * 64;
  int lW = lBase + wn * 64;
#pragma unroll
  for (int m = 0; m < 4; ++m) {
#pragma unroll
    for (int i = 0; i < 4; ++i) {
      int o = oW + m * 16 + quad * 4 + i;
      float bb = projb[o];
#pragma unroll
      for (int n = 0; n < 4; ++n) {
        int l = lW + n * 16 + lrow;
        size_t off = ((size_t)(b * CCH + o)) * LL + l;
        out[off] = acc[m][n][i] + bb + x[off];
      }
    }
  }
}

// ---------------------------------------------------------------------------
extern "C" void kernel_launch(void* const* d_in, const int* in_sizes, int n_in,
                              void* d_out, int out_size, void* d_ws, size_t ws_size,
                              hipStream_t stream) {
  const float* x     = (const float*)d_in[0];
  const float* gsc   = (const float*)d_in[1];
  const float* gbi   = (const float*)d_in[2];
  const float* qkvw  = (const float*)d_in[3];
  const float* qkvb  = (const float*)d_in[4];
  const float* projw = (const float*)d_in[5];
  const float* projb = (const float*)d_in[6];
  float* out = (float*)d_out;

  char* ws = (char*)d_ws;
  bf16_t* wqb   = (bf16_t*)(ws + 4096);
  bf16_t* wpb   = (bf16_t*)(ws + 4096 + 1572864);
  bf16_t* xnT   = (bf16_t*)(ws + 2101248);
  bf16_t* qt    = (bf16_t*)(ws + 2101248 + 8388608);
  bf16_t* kt    = (bf16_t*)(ws + 2101248 + 2 * 8388608);
  bf16_t* vt    = (bf16_t*)(ws + 2101248 + 3 * 8388608);
  bf16_t* at    = (bf16_t*)(ws + 2101248 + 4 * 8388608);

  hipLaunchKernelGGL(prep_fused, dim3(1280), dim3(256), 0, stream,
                     qkvw, projw, wqb, wpb, x, gsc, gbi, xnT);
  hipLaunchKernelGGL(qkv_mfma, dim3(BATCH, 12, 8), dim3(256), 0, stream,
                     wqb, xnT, qkvb, qt, kt, vt);
  hipLaunchKernelGGL(attn_mfma, dim3(64, 8), dim3(256), 0, stream, qt, kt, vt, at);
  hipLaunchKernelGGL(proj_mfma, dim3(BATCH, 4, 8), dim3(256), 0, stream,
                     wpb, at, projb, x, out);
}

// Round 9
// 155.262 us; speedup vs baseline: 1.2282x; 1.0691x over previous
//
#include <hip/hip_runtime.h>
#include <math.h>

// (B,C,H,W)=(8,512,32,32), L=1024, 32 groups, 8 heads, ch=64
#define BATCH   8
#define CCH     512
#define LL      1024
#define NHEADS  8
#define CHD     64
#define EPSV    1e-5f
#define QSCALE  0.1803368801111204f   // 0.125 / ln(2): folded into q so S is in log2 units

typedef __bf16 bf16_t;
typedef bf16_t bf16x8 __attribute__((ext_vector_type(8)));
typedef bf16_t bf16x4 __attribute__((ext_vector_type(4)));
typedef float  f32x4  __attribute__((ext_vector_type(4)));

__device__ __forceinline__ bf16_t f2b(float f) {
  unsigned u = __float_as_uint(f);
  u += 0x7fff + ((u >> 16) & 1);               // RNE
  return __builtin_bit_cast(bf16_t, (unsigned short)(u >> 16));
}

__device__ __forceinline__ unsigned pack2(float lo, float hi) {
  unsigned a = (unsigned)__builtin_bit_cast(unsigned short, f2b(lo));
  unsigned b = (unsigned)__builtin_bit_cast(unsigned short, f2b(hi));
  return (b << 16) | a;
}

__device__ __forceinline__ void gload_lds16(const void* g, void* l) {
  __builtin_amdgcn_global_load_lds(
      (const __attribute__((address_space(1))) void*)g,
      (__attribute__((address_space(3))) void*)l, 16, 0, 0);
}

// ---------------------------------------------------------------------------
// K1: fused prep.  Blocks 0..1023: fp32->bf16 weight convert (qkv_w + proj_w).
// Blocks 1024..1279: GroupNorm stats+normalize+affine+transpose -> xnT bf16.
// ---------------------------------------------------------------------------
__global__ __launch_bounds__(256) void prep_fused(const float* __restrict__ qkvw,
                                                  const float* __restrict__ projw,
                                                  bf16_t* __restrict__ wqb,
                                                  bf16_t* __restrict__ wpb,
                                                  const float* __restrict__ x,
                                                  const float* __restrict__ gsc,
                                                  const float* __restrict__ gbi,
                                                  bf16_t* __restrict__ xnT) {
  int bid = blockIdx.x;
  int tid = threadIdx.x;
  if (bid < 1024) {
    int i = (bid * 256 + tid) * 4;
    const float* src;
    bf16_t* dst;
    int j;
    if (i < 1536 * 512) { src = qkvw; dst = wqb; j = i; }
    else                { src = projw; dst = wpb; j = i - 1536 * 512; }
    float4 v = *(const float4*)(src + j);
    bf16x4 o = {f2b(v.x), f2b(v.y), f2b(v.z), f2b(v.w)};
    *(bf16x4*)(dst + j) = o;
    return;
  }
  int lin = bid - 1024;
  int xcd = lin & 7, slot = lin >> 3;
  int b = slot & 7, jj = slot >> 3;
  int g = xcd * 4 + jj;
  const float4* x4 = (const float4*)(x + ((size_t)(b * 32 + g)) * 16 * LL);

  float s = 0.f, ss = 0.f;
  float4 v[16];
#pragma unroll
  for (int it = 0; it < 16; ++it) {
    float4 f = x4[it * 256 + tid];
    v[it] = f;
    s += f.x + f.y + f.z + f.w;
    ss += f.x * f.x + f.y * f.y + f.z * f.z + f.w * f.w;
  }
#pragma unroll
  for (int m = 1; m < 64; m <<= 1) { s += __shfl_xor(s, m); ss += __shfl_xor(ss, m); }
  __shared__ float rs_[4], rss[4];
  int wv = tid >> 6, ln = tid & 63;
  if (ln == 0) { rs_[wv] = s; rss[wv] = ss; }
  __syncthreads();
  s  = rs_[0] + rs_[1] + rs_[2] + rs_[3];
  ss = rss[0] + rss[1] + rss[2] + rss[3];
  float mean = s * (1.f / 16384.f);
  float var  = ss * (1.f / 16384.f) - mean * mean;
  float rstd = rsqrtf(var + EPSV);

  float sc[16], bi[16];
#pragma unroll
  for (int it = 0; it < 16; ++it) {
    sc[it] = gsc[g * 16 + it] * rstd;
    bi[it] = gbi[g * 16 + it] - mean * sc[it];
  }

#pragma unroll
  for (int j = 0; j < 4; ++j) {
    unsigned w[8];
#pragma unroll
    for (int k = 0; k < 8; ++k) {
      float a0 = (j == 0 ? v[2 * k].x : j == 1 ? v[2 * k].y : j == 2 ? v[2 * k].z : v[2 * k].w);
      float a1 = (j == 0 ? v[2 * k + 1].x : j == 1 ? v[2 * k + 1].y : j == 2 ? v[2 * k + 1].z : v[2 * k + 1].w);
      w[k] = pack2(a0 * sc[2 * k] + bi[2 * k], a1 * sc[2 * k + 1] + bi[2 * k + 1]);
    }
    int l = tid * 4 + j;
    bf16_t* dst = xnT + ((size_t)b * LL + l) * CCH + g * 16;
    *(uint4*)dst = make_uint4(w[0], w[1], w[2], w[3]);
    *(uint4*)(dst + 8) = make_uint4(w[4], w[5], w[6], w[7]);
  }
}

// ---------------------------------------------------------------------------
// K2: qkv GEMM (MFMA).  128x256 block tile, BK=64; wave tile 64x128 (4m x 8n)
// -> 24 ds_read_b128 per 64 MFMA per wave-ktile (MFMA-side-bound).  Grid
// (x=b, y=ot(12), z=lt(4)) so linear%8 == b (XCD/L2 locality on xnT[b]).
// global_load_lds w16, XOR-granule swizzle on the global source.
// Epilogue: b64 packed stores; q scaled by QSCALE; v transposed+s-permuted.
// ---------------------------------------------------------------------------
__global__ __launch_bounds__(256, 2) void qkv_mfma(const bf16_t* __restrict__ wq,
                                                   const bf16_t* __restrict__ xnT,
                                                   const float* __restrict__ qkvb,
                                                   bf16_t* __restrict__ qt,
                                                   bf16_t* __restrict__ kt,
                                                   bf16_t* __restrict__ vt) {
  __shared__ bf16_t As[128 * 64];   // [row o][c], 128-B rows, granule-swizzled
  __shared__ bf16_t Bs[256 * 64];   // [row l][c]
  int tid = threadIdx.x;
  int wave = tid >> 6, lane = tid & 63;
  int lrow = lane & 15, quad = lane >> 4;
  int wm = wave >> 1, wn = wave & 1;
  int b = blockIdx.x;
  int oBase = blockIdx.y * 128, lBase = blockIdx.z * 256;
  int srow = lane >> 3;
  int sgOff = (((lane & 7) ^ srow) << 4);

  f32x4 acc[4][8] = {};
  for (int ktile = 0; ktile < 8; ++ktile) {
    int kB = ktile * 64;
    __syncthreads();
#pragma unroll
    for (int j = 0; j < 4; ++j) {               // As: 16 chunks, 4/wave
      int ci = wave * 4 + j;
      int R = ci * 8 + srow;
      gload_lds16((const char*)(wq + (size_t)(oBase + R) * CCH + kB) + sgOff,
                  (char*)As + ci * 1024);
    }
#pragma unroll
    for (int j = 0; j < 8; ++j) {               // Bs: 32 chunks, 8/wave
      int ci = wave * 8 + j;
      int R = ci * 8 + srow;
      gload_lds16((const char*)(xnT + ((size_t)b * LL + lBase + R) * CCH + kB) + sgOff,
                  (char*)Bs + ci * 1024);
    }
    __syncthreads();
#pragma unroll
    for (int kk = 0; kk < 2; ++kk) {
      int g = (kk * 4 + quad) ^ (lrow & 7);
      bf16x8 af[4], bfr[8];
#pragma unroll
      for (int m = 0; m < 4; ++m) {
        int r = wm * 64 + m * 16 + lrow;
        af[m] = *(const bf16x8*)(As + r * 64 + g * 8);
      }
#pragma unroll
      for (int n = 0; n < 8; ++n) {
        int r = wn * 128 + n * 16 + lrow;
        bfr[n] = *(const bf16x8*)(Bs + r * 64 + g * 8);
      }
#pragma unroll
      for (int m = 0; m < 4; ++m)
#pragma unroll
        for (int n = 0; n < 8; ++n)
          acc[m][n] = __builtin_amdgcn_mfma_f32_16x16x32_bf16(af[m], bfr[n], acc[m][n], 0, 0, 0);
    }
  }

  int oW = oBase + wm * 64;
  int lW = lBase + wn * 128;
  int sec = oW >> 9;                            // wave-uniform
#pragma unroll
  for (int m = 0; m < 4; ++m) {
    int o4 = oW + m * 16 + quad * 4;
    float4 bb4 = *(const float4*)&qkvb[o4];
    int cc = o4 & 511;
    int head = cc >> 6, ch = cc & 63;
    int bh = b * NHEADS + head;
    if (sec == 0) {
#pragma unroll
      for (int n = 0; n < 8; ++n) {
        int l = lW + n * 16 + lrow;
        unsigned d0 = pack2((acc[m][n][0] + bb4.x) * QSCALE,
                            (acc[m][n][1] + bb4.y) * QSCALE);
        unsigned d1 = pack2((acc[m][n][2] + bb4.z) * QSCALE,
                            (acc[m][n][3] + bb4.w) * QSCALE);
        *(uint2*)(qt + ((size_t)bh * LL + l) * CHD + ch) = make_uint2(d0, d1);
      }
    } else if (sec == 1) {
#pragma unroll
      for (int n = 0; n < 8; ++n) {
        int l = lW + n * 16 + lrow;
        unsigned d0 = pack2(acc[m][n][0] + bb4.x, acc[m][n][1] + bb4.y);
        unsigned d1 = pack2(acc[m][n][2] + bb4.z, acc[m][n][3] + bb4.w);
        *(uint2*)(kt + ((size_t)bh * LL + l) * CHD + ch) = make_uint2(d0, d1);
      }
    } else {
      // v: within each 64-l chunk, lp = (l&~63) | lrow*4 | (n&3); chunk = n>>2
      float bb[4] = {bb4.x, bb4.y, bb4.z, bb4.w};
#pragma unroll
      for (int c = 0; c < 2; ++c) {
#pragma unroll
        for (int i = 0; i < 4; ++i) {
          unsigned d0 = pack2(acc[m][c * 4 + 0][i] + bb[i], acc[m][c * 4 + 1][i] + bb[i]);
          unsigned d1 = pack2(acc[m][c * 4 + 2][i] + bb[i], acc[m][c * 4 + 3][i] + bb[i]);
          *(uint2*)(vt + ((size_t)bh * CHD + ch + i) * LL + lW + c * 64 + lrow * 4) =
              make_uint2(d0, d1);
        }
      }
    }
  }
}

// ---------------------------------------------------------------------------
// K3: flash attention (MFMA), no-max softmax in log2 units.  (R6 proven best)
// Block = (bh, 128 q-rows); wave owns 32 q-rows (2 subtiles h) so each K/V
// LDS fragment feeds 2x MFMA work.  Grid (x=bh, y=t-tile): linear%8 == bh%8
// (XCD locality, K/V 2 MB/XCD in L2).  K and V double-buffered in LDS via
// global_load_lds w16 + XOR-granule swizzle (decouples load from consume;
// direct-global variants measured slower in R3/R7/R8).  exp2-only softmax;
// row-sum via ones-MFMA; P through wave-private LDS, s-permuted to match vt.
// ---------------------------------------------------------------------------
__global__ __launch_bounds__(256) void attn_mfma(const bf16_t* __restrict__ qt,
                                                 const bf16_t* __restrict__ kt,
                                                 const bf16_t* __restrict__ vt,
                                                 bf16_t* __restrict__ at) {
  __shared__ bf16_t kbuf[2][64 * 64];
  __shared__ bf16_t vbuf[2][64 * 64];
  __shared__ bf16_t pb[8 * 16 * 72];            // per (wave,h) P tile, stride 72
  int tid = threadIdx.x, wave = tid >> 6, lane = tid & 63;
  int lrow = lane & 15, quad = lane >> 4;
  int bh = blockIdx.x;
  int tW = blockIdx.y * 128 + wave * 32;
  const bf16_t* qb = qt + (size_t)bh * LL * CHD;
  const bf16_t* kb = kt + (size_t)bh * LL * CHD;
  const bf16_t* vb = vt + (size_t)bh * CHD * LL;

  int srow = lane >> 3;
  int sgb = (((lane & 7) ^ srow) << 4);

  bf16x8 qf[2][2];
#pragma unroll
  for (int h = 0; h < 2; ++h) {
    const bf16_t* qp = qb + (size_t)(tW + h * 16 + lrow) * CHD + quad * 8;
    qf[h][0] = *(const bf16x8*)qp;
    qf[h][1] = *(const bf16x8*)(qp + 32);
  }

  bf16x8 ones;
#pragma unroll
  for (int j = 0; j < 8; ++j) ones[j] = (bf16_t)1.0f;

  f32x4 Oa[2][4] = {};
  f32x4 Os[2] = {};

#pragma unroll
  for (int j = 0; j < 2; ++j) {
    int c = wave * 2 + j;
    int R = c * 8 + srow;
    gload_lds16((const char*)(kb + (size_t)R * CHD) + sgb, (char*)&kbuf[0][0] + c * 1024);
    gload_lds16((const char*)(vb + (size_t)R * LL) + sgb, (char*)&vbuf[0][0] + c * 1024);
  }
  __syncthreads();

  int swz0 = (quad ^ (lrow & 7)) * 8;
  int swz1 = ((quad + 4) ^ (lrow & 7)) * 8;

  for (int st = 0; st < 16; ++st) {
    int cur = st & 1;
    if (st < 15) {
      int sBn = (st + 1) * 64;
#pragma unroll
      for (int j = 0; j < 2; ++j) {
        int c = wave * 2 + j;
        int R = c * 8 + srow;
        gload_lds16((const char*)(kb + (size_t)(sBn + R) * CHD) + sgb,
                    (char*)&kbuf[cur ^ 1][0] + c * 1024);
        gload_lds16((const char*)(vb + (size_t)R * LL + sBn) + sgb,
                    (char*)&vbuf[cur ^ 1][0] + c * 1024);
      }
    }
    const bf16_t* kbase = &kbuf[cur][0];
    const bf16_t* vbase = &vbuf[cur][0];

    f32x4 S[2][4];
#pragma unroll
    for (int ss = 0; ss < 4; ++ss) {
      int s = ss * 16 + lrow;
      bf16x8 k0 = *(const bf16x8*)(kbase + s * 64 + swz0);
      bf16x8 k1 = *(const bf16x8*)(kbase + s * 64 + swz1);
#pragma unroll
      for (int h = 0; h < 2; ++h) {
        f32x4 z = {0.f, 0.f, 0.f, 0.f};
        z = __builtin_amdgcn_mfma_f32_16x16x32_bf16(qf[h][0], k0, z, 0, 0, 0);
        S[h][ss] = __builtin_amdgcn_mfma_f32_16x16x32_bf16(qf[h][1], k1, z, 0, 0, 0);
      }
    }

#pragma unroll
    for (int h = 0; h < 2; ++h) {
      bf16_t* pw = pb + (wave * 2 + h) * (16 * 72);
      float p[4][4];
#pragma unroll
      for (int ss = 0; ss < 4; ++ss)
#pragma unroll
        for (int i = 0; i < 4; ++i)
          p[ss][i] = __builtin_amdgcn_exp2f(S[h][ss][i]);
#pragma unroll
      for (int i = 0; i < 4; ++i) {
        unsigned d0 = __builtin_amdgcn_perm(__float_as_uint(p[1][i]),
                                            __float_as_uint(p[0][i]), 0x07060302u);
        unsigned d1 = __builtin_amdgcn_perm(__float_as_uint(p[3][i]),
                                            __float_as_uint(p[2][i]), 0x07060302u);
        uint2* dst = (uint2*)(pw + (quad * 4 + i) * 72 + lrow * 4);
        *dst = make_uint2(d0, d1);
      }
    }
    asm volatile("s_waitcnt lgkmcnt(0)" ::: "memory");   // wave-private P

    bf16x8 pf[2][2];
#pragma unroll
    for (int h = 0; h < 2; ++h) {
      const bf16_t* pw = pb + (wave * 2 + h) * (16 * 72);
      pf[h][0] = *(const bf16x8*)(pw + lrow * 72 + quad * 8);
      pf[h][1] = *(const bf16x8*)(pw + lrow * 72 + 32 + quad * 8);
    }

#pragma unroll
    for (int n = 0; n < 4; ++n) {
      int r = (n * 16 + lrow) * 64;
      bf16x8 v0 = *(const bf16x8*)(vbase + r + swz0);
      bf16x8 v1 = *(const bf16x8*)(vbase + r + swz1);
#pragma unroll
      for (int h = 0; h < 2; ++h) {
        Oa[h][n] = __builtin_amdgcn_mfma_f32_16x16x32_bf16(pf[h][0], v0, Oa[h][n], 0, 0, 0);
        Oa[h][n] = __builtin_amdgcn_mfma_f32_16x16x32_bf16(pf[h][1], v1, Oa[h][n], 0, 0, 0);
      }
    }
#pragma unroll
    for (int h = 0; h < 2; ++h) {
      Os[h] = __builtin_amdgcn_mfma_f32_16x16x32_bf16(pf[h][0], ones, Os[h], 0, 0, 0);
      Os[h] = __builtin_amdgcn_mfma_f32_16x16x32_bf16(pf[h][1], ones, Os[h], 0, 0, 0);
    }

    __syncthreads();
  }

  bf16_t* ab = at + (size_t)bh * LL * CHD;
#pragma unroll
  for (int h = 0; h < 2; ++h) {
    float inv[4];
#pragma unroll
    for (int i = 0; i < 4; ++i) inv[i] = 1.f / Os[h][i];
#pragma unroll
    for (int n = 0; n < 4; ++n)
#pragma unroll
      for (int i = 0; i < 4; ++i)
        ab[(size_t)(tW + h * 16 + quad * 4 + i) * CHD + n * 16 + lrow] =
            f2b(Oa[h][n][i] * inv[i]);
  }
}

// ---------------------------------------------------------------------------
// K4: proj GEMM (MFMA) + bias + fp32 residual, LDS-staged.
// BK=64 == one head of at.  Grid (x=b, y=ot, z=lt), linear%8 == b.
// ---------------------------------------------------------------------------
__global__ __launch_bounds__(256) void proj_mfma(const bf16_t* __restrict__ wp,
                                                 const bf16_t* __restrict__ at,
                                                 const float* __restrict__ projb,
                                                 const float* __restrict__ x,
                                                 float* __restrict__ out) {
  __shared__ bf16_t As[128 * 64];
  __shared__ bf16_t Bs[128 * 64];
  int tid = threadIdx.x;
  int wave = tid >> 6, lane = tid & 63;
  int lrow = lane & 15, quad = lane >> 4;
  int wm = wave >> 1, wn = wave & 1;
  int b = blockIdx.x;
  int oBase = blockIdx.y * 128, lBase = blockIdx.z * 128;
  int srow = lane >> 3;
  int sgOff = (((lane & 7) ^ srow) << 4);

  f32x4 acc[4][4] = {};
  for (int ktile = 0; ktile < 8; ++ktile) {     // head = ktile
    int kB = ktile * 64;
    __syncthreads();
#pragma unroll
    for (int j = 0; j < 4; ++j) {
      int ci = wave * 4 + j;
      int R = ci * 8 + srow;
      gload_lds16((const char*)(wp + (size_t)(oBase + R) * CCH + kB) + sgOff,
                  (char*)As + ci * 1024);
      gload_lds16((const char*)(at + ((size_t)(b * NHEADS + ktile) * LL + lBase + R) * CHD) + sgOff,
                  (char*)Bs + ci * 1024);
    }
    __syncthreads();
#pragma unroll
    for (int kk = 0; kk < 2; ++kk) {
      int g = (kk * 4 + quad) ^ (lrow & 7);
      bf16x8 af[4], bfr[4];
#pragma unroll
      for (int m = 0; m < 4; ++m) {
        int r = wm * 64 + m * 16 + lrow;
        af[m] = *(const bf16x8*)(As + r * 64 + g * 8);
      }
#pragma unroll
      for (int n = 0; n < 4; ++n) {
        int r = wn * 64 + n * 16 + lrow;
        bfr[n] = *(const bf16x8*)(Bs + r * 64 + g * 8);
      }
#pragma unroll
      for (int m = 0; m < 4; ++m)
#pragma unroll
        for (int n = 0; n < 4; ++n)
          acc[m][n] = __builtin_amdgcn_mfma_f32_16x16x32_bf16(af[m], bfr[n], acc[m][n], 0, 0, 0);
    }
  }

  int oW = oBase + wm * 64;
  int lW = lBase + wn * 64;
#pragma unroll
  for (int m = 0; m < 4; ++m) {
#pragma unroll
    for (int i = 0; i < 4; ++i) {
      int o = oW + m * 16 + quad * 4 + i;
      float bb = projb[o];
#pragma unroll
      for (int n = 0; n < 4; ++n) {
        int l = lW + n * 16 + lrow;
        size_t off = ((size_t)(b * CCH + o)) * LL + l;
        out[off] = acc[m][n][i] + bb + x[off];
      }
    }
  }
}

// ---------------------------------------------------------------------------
extern "C" void kernel_launch(void* const* d_in, const int* in_sizes, int n_in,
                              void* d_out, int out_size, void* d_ws, size_t ws_size,
                              hipStream_t stream) {
  const float* x     = (const float*)d_in[0];
  const float* gsc   = (const float*)d_in[1];
  const float* gbi   = (const float*)d_in[2];
  const float* qkvw  = (const float*)d_in[3];
  const float* qkvb  = (const float*)d_in[4];
  const float* projw = (const float*)d_in[5];
  const float* projb = (const float*)d_in[6];
  float* out = (float*)d_out;

  char* ws = (char*)d_ws;
  bf16_t* wqb   = (bf16_t*)(ws + 4096);
  bf16_t* wpb   = (bf16_t*)(ws + 4096 + 1572864);
  bf16_t* xnT   = (bf16_t*)(ws + 2101248);
  bf16_t* qt    = (bf16_t*)(ws + 2101248 + 8388608);
  bf16_t* kt    = (bf16_t*)(ws + 2101248 + 2 * 8388608);
  bf16_t* vt    = (bf16_t*)(ws + 2101248 + 3 * 8388608);
  bf16_t* at    = (bf16_t*)(ws + 2101248 + 4 * 8388608);

  hipLaunchKernelGGL(prep_fused, dim3(1280), dim3(256), 0, stream,
                     qkvw, projw, wqb, wpb, x, gsc, gbi, xnT);
  hipLaunchKernelGGL(qkv_mfma, dim3(BATCH, 12, 4), dim3(256), 0, stream,
                     wqb, xnT, qkvb, qt, kt, vt);
  hipLaunchKernelGGL(attn_mfma, dim3(64, 8), dim3(256), 0, stream, qt, kt, vt, at);
  hipLaunchKernelGGL(proj_mfma, dim3(BATCH, 4, 8), dim3(256), 0, stream,
                     wpb, at, projb, x, out);
}